// Round 1
// 1505.445 us; speedup vs baseline: 1.4780x; 1.4780x over previous
//
#include <hip/hip_runtime.h>
#include <math.h>

#define Bsz 64
#define Pp  196
#define ENC 2048
#define Ee  512
#define Hh  512
#define Vv  10000
#define Tt  20
#define H4  2048

typedef short bf16x8 __attribute__((ext_vector_type(8)));
typedef float f32x4 __attribute__((ext_vector_type(4)));

__device__ __forceinline__ float sigmoidf_(float x) { return 1.0f / (1.0f + expf(-x)); }

__device__ __forceinline__ unsigned short bf16r(float x) {
    union { float f; unsigned int u; } c; c.f = x;
    unsigned int lsb = (c.u >> 16) & 1u;
    return (unsigned short)((c.u + 0x7fffu + lsb) >> 16);
}

// ---------------- v_enc[e] = sum_a W_full[a] * W_enc[a][e] ----------------
__global__ __launch_bounds__(256) void k_venc(const float* __restrict__ W_full,
                                              const float* __restrict__ W_enc,
                                              float* __restrict__ v_enc) {
    int lane = threadIdx.x & 63, ag = threadIdx.x >> 6;
    int e = blockIdx.x * 64 + lane;
    float s = 0.f;
    #pragma unroll 8
    for (int a = ag * 128; a < ag * 128 + 128; ++a)
        s += W_full[a] * W_enc[(size_t)a * ENC + e];
    __shared__ float red[4][64];
    red[ag][lane] = s;
    __syncthreads();
    if (threadIdx.x < 64)
        v_enc[e] = red[0][lane] + red[1][lane] + red[2][lane] + red[3][lane];
}

// ---------------- scores: sc[b][p] = dot(img[b][p], v_enc) ----------------
__global__ __launch_bounds__(256) void k_scores(const float* __restrict__ img,
                                                const float* __restrict__ v_enc,
                                                float* __restrict__ sc) {
    int b = blockIdx.y;
    int wave = threadIdx.x >> 6, lane = threadIdx.x & 63;
    int p = blockIdx.x * 4 + wave;
    __shared__ float4 sv[ENC / 4];
    const float4* ve4 = (const float4*)v_enc;
    sv[threadIdx.x] = ve4[threadIdx.x];
    sv[threadIdx.x + 256] = ve4[threadIdx.x + 256];
    __syncthreads();
    const float4* row = (const float4*)(img + ((size_t)b * Pp + p) * ENC);
    float s = 0.f;
    #pragma unroll
    for (int it = 0; it < 8; ++it) {
        int idx = it * 64 + lane;
        float4 v = row[idx];
        float4 w = sv[idx];
        s += v.x * w.x + v.y * w.y + v.z * w.z + v.w * w.w;
    }
    #pragma unroll
    for (int off = 32; off > 0; off >>= 1) s += __shfl_down(s, off);
    if (lane == 0) sc[b * Pp + p] = s;
}

// ---------------- softmax over p; writes alpha + broadcast alphas_out ----------------
__global__ __launch_bounds__(256) void k_softmax(const float* __restrict__ sc,
                                                 float* __restrict__ alpha,
                                                 float* __restrict__ alphas_out) {
    int b = blockIdx.x, tid = threadIdx.x;
    __shared__ float red[256];
    __shared__ float sa[Pp];
    float v = (tid < Pp) ? sc[b * Pp + tid] : -INFINITY;
    red[tid] = v; __syncthreads();
    for (int off = 128; off > 0; off >>= 1) {
        if (tid < off) red[tid] = fmaxf(red[tid], red[tid + off]);
        __syncthreads();
    }
    float mx = red[0]; __syncthreads();
    float ex = (tid < Pp) ? expf(v - mx) : 0.f;
    red[tid] = ex; __syncthreads();
    for (int off = 128; off > 0; off >>= 1) {
        if (tid < off) red[tid] += red[tid + off];
        __syncthreads();
    }
    float inv = 1.f / red[0];
    if (tid < Pp) { sa[tid] = ex * inv; alpha[b * Pp + tid] = ex * inv; }
    __syncthreads();
    for (int i = tid; i < Tt * Pp; i += 256)
        alphas_out[(size_t)b * Tt * Pp + i] = sa[i % Pp];
}

// ---------------- context + avg ----------------
__global__ __launch_bounds__(256) void k_ctx(const float* __restrict__ img,
                                             const float* __restrict__ alpha,
                                             float* __restrict__ context,
                                             float* __restrict__ avg) {
    int b = blockIdx.y;
    int e2 = blockIdx.x * 256 + threadIdx.x;
    __shared__ float sa[Pp];
    if (threadIdx.x < Pp) sa[threadIdx.x] = alpha[b * Pp + threadIdx.x];
    __syncthreads();
    const float2* ib2 = (const float2*)(img + (size_t)b * Pp * ENC);
    float cx = 0.f, cy = 0.f, ax = 0.f, ay = 0.f;
    for (int p = 0; p < Pp; p += 4) {
        #pragma unroll
        for (int q = 0; q < 4; ++q) {
            float ap = sa[p + q];
            float2 v = ib2[(size_t)(p + q) * (ENC / 2) + e2];
            cx += ap * v.x; cy += ap * v.y;
            ax += v.x;      ay += v.y;
        }
    }
    float2* c2 = (float2*)(context + (size_t)b * ENC);
    float2* a2 = (float2*)(avg + (size_t)b * ENC);
    c2[e2] = make_float2(cx, cy);
    a2[e2] = make_float2(ax * (1.f / 196.f), ay * (1.f / 196.f));
}

// ---------------- small-M GEMM family: BM=64, BN=16, BK=64, TM=4 ----------------
// MODE 0 (INIT): hc[64,1024] = avg @ [Winit_h|Winit_c]^T + bias  (K=2048)
// MODE 1 (G1):   N=4096 over [W_beta | W_hh], K=512.
//                n<2048: gc = sigmoid(acc+b_beta)*context ; n>=2048: P[0] = acc
// MODE 2 (G2):   z=blockIdx.y in [0,4): P[1+z] = gc[:, z*512:+512] @ W_ih[:,512+z*512:+512]^T
template<int MODE>
__global__ __launch_bounds__(256) void gemm_step(
    const float* __restrict__ A,
    const float* __restrict__ B0, const float* __restrict__ B1,
    float* __restrict__ C, float* __restrict__ P,
    const float* __restrict__ bias0, const float* __restrict__ bias1,
    const float* __restrict__ extra) {
    const int tid = threadIdx.x;
    const int tx = tid & 15, ty = tid >> 4;
    const int n0 = blockIdx.x * 16;

    int lda, ldb, nch, kbase = 0;
    const float* Brow;
    if (MODE == 0) {
        lda = 2048; ldb = 2048; nch = 32;
        Brow = (n0 < 512) ? B0 + (size_t)n0 * 2048 : B1 + (size_t)(n0 - 512) * 2048;
    } else if (MODE == 1) {
        lda = 1024; ldb = 512; nch = 8;
        Brow = (n0 < 2048) ? B0 + (size_t)n0 * 512 : B1 + (size_t)(n0 - 2048) * 512;
    } else {
        lda = 2048; ldb = 2560; nch = 8; kbase = blockIdx.y * 512;
        Brow = B0 + (size_t)n0 * 2560 + 512 + kbase;
    }

    __shared__ float As[64][68];
    __shared__ float Bs[64][20];

    float4 pa[4], pb;
    const int sm[4] = { tid >> 4, (256 + tid) >> 4, (512 + tid) >> 4, (768 + tid) >> 4 };
    const int scc = tid & 15;
    const int bn = tid >> 4, bc = tid & 15;

    auto load_chunk = [&](int c) {
        int k0 = c * 64;
        #pragma unroll
        for (int i = 0; i < 4; ++i)
            pa[i] = *(const float4*)(A + (size_t)sm[i] * lda + kbase + k0 + 4 * scc);
        pb = *(const float4*)(Brow + (size_t)bn * ldb + k0 + 4 * bc);
    };

    float acc[4] = {};
    load_chunk(0);
    for (int c = 0; c < nch; ++c) {
        __syncthreads();
        #pragma unroll
        for (int i = 0; i < 4; ++i) {
            As[4 * scc + 0][sm[i]] = pa[i].x;
            As[4 * scc + 1][sm[i]] = pa[i].y;
            As[4 * scc + 2][sm[i]] = pa[i].z;
            As[4 * scc + 3][sm[i]] = pa[i].w;
        }
        Bs[4 * bc + 0][bn] = pb.x;
        Bs[4 * bc + 1][bn] = pb.y;
        Bs[4 * bc + 2][bn] = pb.z;
        Bs[4 * bc + 3][bn] = pb.w;
        __syncthreads();
        if (c + 1 < nch) load_chunk(c + 1);
        #pragma unroll 8
        for (int kk = 0; kk < 64; ++kk) {
            float4 a = *(const float4*)&As[kk][ty * 4];
            float bb = Bs[kk][tx];
            acc[0] += a.x * bb; acc[1] += a.y * bb;
            acc[2] += a.z * bb; acc[3] += a.w * bb;
        }
    }

    int gn = n0 + tx;
    #pragma unroll
    for (int i = 0; i < 4; ++i) {
        int m = ty * 4 + i;
        if (MODE == 0) {
            float bsel = (n0 < 512) ? bias0[gn] : bias1[gn - 512];
            C[(size_t)m * 1024 + gn] = acc[i] + bsel;
        } else if (MODE == 1) {
            if (n0 < 2048) {
                float s = sigmoidf_(acc[i] + bias0[gn]);
                C[(size_t)m * 2048 + gn] = s * extra[(size_t)m * 2048 + gn];
            } else {
                P[(size_t)m * 2048 + gn - 2048] = acc[i];
            }
        } else {
            P[(size_t)(blockIdx.y + 1) * (64 * 2048) + (size_t)m * 2048 + gn] = acc[i];
        }
    }
}

// ---------------- emb GEMM with fused gather: BM=128, BN=64, BK=32 ----------------
// emb_part[t*64+b][n] = embedding[captions[b][t]] . W_ih[n][0:512] + b_ih[n] + b_hh[n]
__global__ __launch_bounds__(256) void gemm_emb(const int* __restrict__ captions,
                                                const float* __restrict__ emb,
                                                const float* __restrict__ Bm,
                                                float* __restrict__ C,
                                                const float* __restrict__ bias,
                                                const float* __restrict__ bias2) {
    const int tid = threadIdx.x;
    const int tx = tid & 15, ty = tid >> 4;
    const int m0 = blockIdx.y * 128, n0 = blockIdx.x * 64;

    __shared__ float As[32][132];
    __shared__ float Bs[32][68];

    float4 pa[4], pb[2];
    const int am[4] = { tid >> 3, (256 + tid) >> 3, (512 + tid) >> 3, (768 + tid) >> 3 };
    const int ac = tid & 7;
    const int bnr[2] = { tid >> 3, (256 + tid) >> 3 };
    const int bc = tid & 7;

    const float* arow[4];
    #pragma unroll
    for (int i = 0; i < 4; ++i) {
        int r = m0 + am[i];
        arow[i] = emb + (size_t)captions[(r & 63) * Tt + (r >> 6)] * Ee;
    }

    const int nchunk = Ee / 32;
    auto load_chunk = [&](int c) {
        int k0 = c * 32;
        #pragma unroll
        for (int i = 0; i < 4; ++i)
            pa[i] = *(const float4*)(arow[i] + k0 + 4 * ac);
        #pragma unroll
        for (int i = 0; i < 2; ++i)
            pb[i] = *(const float4*)(Bm + (size_t)(n0 + bnr[i]) * 2560 + k0 + 4 * bc);
    };

    float acc[8][4] = {};
    load_chunk(0);
    for (int c = 0; c < nchunk; ++c) {
        __syncthreads();
        #pragma unroll
        for (int i = 0; i < 4; ++i) {
            As[4 * ac + 0][am[i]] = pa[i].x;
            As[4 * ac + 1][am[i]] = pa[i].y;
            As[4 * ac + 2][am[i]] = pa[i].z;
            As[4 * ac + 3][am[i]] = pa[i].w;
        }
        #pragma unroll
        for (int i = 0; i < 2; ++i) {
            Bs[4 * bc + 0][bnr[i]] = pb[i].x;
            Bs[4 * bc + 1][bnr[i]] = pb[i].y;
            Bs[4 * bc + 2][bnr[i]] = pb[i].z;
            Bs[4 * bc + 3][bnr[i]] = pb[i].w;
        }
        __syncthreads();
        if (c + 1 < nchunk) load_chunk(c + 1);
        #pragma unroll 4
        for (int kk = 0; kk < 32; ++kk) {
            float4 a0 = *(const float4*)&As[kk][ty * 8];
            float4 a1 = *(const float4*)&As[kk][ty * 8 + 4];
            float4 b0 = *(const float4*)&Bs[kk][tx * 4];
            float av[8] = { a0.x, a0.y, a0.z, a0.w, a1.x, a1.y, a1.z, a1.w };
            float bv[4] = { b0.x, b0.y, b0.z, b0.w };
            #pragma unroll
            for (int i = 0; i < 8; ++i)
                #pragma unroll
                for (int j = 0; j < 4; ++j)
                    acc[i][j] += av[i] * bv[j];
        }
    }

    #pragma unroll
    for (int i = 0; i < 8; ++i) {
        int m = m0 + ty * 8 + i;
        #pragma unroll
        for (int j = 0; j < 4; ++j) {
            int gn = n0 + tx * 4 + j;
            C[(size_t)m * H4 + gn] = acc[i][j] + bias[gn] + bias2[gn];
        }
    }
}

// ---------------- LSTM pointwise: sum emb part + 5 GEMM partials ----------------
__global__ __launch_bounds__(256) void k_lstm(const float* __restrict__ ep,
                                              const float* __restrict__ P,
                                              float* __restrict__ hc,
                                              unsigned short* __restrict__ Hbf) {
    int idx = blockIdx.x * 256 + threadIdx.x;  // < 64*512
    int b = idx >> 9, j = idx & 511;
    const float* e = ep + (size_t)b * 2048;
    const float* p0 = P + (size_t)b * 2048;
    const float* p1 = p0 + 64 * 2048;
    const float* p2 = p1 + 64 * 2048;
    const float* p3 = p2 + 64 * 2048;
    const float* p4 = p3 + 64 * 2048;
    auto gsum = [&](int col) {
        return e[col] + p0[col] + p1[col] + p2[col] + p3[col] + p4[col];
    };
    float i_ = sigmoidf_(gsum(j));
    float f_ = sigmoidf_(gsum(j + 512));
    float g_ = tanhf(gsum(j + 1024));
    float o_ = sigmoidf_(gsum(j + 1536));
    float* hrow = hc + (size_t)b * 1024;
    float cn = f_ * hrow[512 + j] + i_ * g_;
    float hn = o_ * tanhf(cn);
    hrow[512 + j] = cn;
    hrow[j] = hn;
    Hbf[(size_t)b * Hh + j] = bf16r(hn);
}

// ---------------- W_out fp32 -> bf16 ----------------
__global__ __launch_bounds__(256) void k_cvt(const float* __restrict__ src,
                                             unsigned short* __restrict__ dst) {
    int i = blockIdx.x * 256 + threadIdx.x;   // 4 elements each; total 5,120,000
    if (i >= (Vv * Hh) / 4) return;
    float4 v = ((const float4*)src)[i];
    ushort4 o;
    o.x = bf16r(v.x); o.y = bf16r(v.y); o.z = bf16r(v.z); o.w = bf16r(v.w);
    ((ushort4*)dst)[i] = o;
}

// ---------------- preds: bf16 MFMA GEMM, 128x128 tile, BK=32 ----------------
// C[b*20+t][n] = sum_k H[t*64+b][k] * Wout[n][k] + b_out[n]
__global__ __launch_bounds__(256) void gemm_preds(const unsigned short* __restrict__ Hb,
                                                  const unsigned short* __restrict__ Wb,
                                                  const float* __restrict__ b_out,
                                                  float* __restrict__ preds) {
    const int tid = threadIdx.x;
    const int lane = tid & 63, wave = tid >> 6;
    const int wr = wave >> 1, wc = wave & 1;             // 2x2 waves, 64x64 each
    const int m0 = blockIdx.y * 128, n0 = blockIdx.x * 128;

    __shared__ unsigned short As[128][40];               // 80 B row stride (16B-aligned, conflict-spread)
    __shared__ unsigned short Bs[128][40];

    const int r0 = tid >> 2, c8 = (tid & 3) * 8;         // stage 2x16B per array per thread
    uint4 pa[2], pb[2];
    auto load = [&](int c) {
        int k0 = c * 32;
        #pragma unroll
        for (int i = 0; i < 2; ++i) {
            int r = r0 + i * 64;
            pa[i] = *(const uint4*)(Hb + (size_t)(m0 + r) * 512 + k0 + c8);
            int gn = n0 + r; gn = (gn > Vv - 1) ? (Vv - 1) : gn;
            pb[i] = *(const uint4*)(Wb + (size_t)gn * 512 + k0 + c8);
        }
    };

    union F8 { bf16x8 v; struct { unsigned long long lo, hi; } u; };
    f32x4 acc[4][4] = {};

    const int arow = wr * 64 + (lane & 15);
    const int brow = wc * 64 + (lane & 15);
    const int kg = (lane >> 4) * 4;                      // element offset within k-halves

    load(0);
    for (int c = 0; c < 16; ++c) {
        __syncthreads();
        #pragma unroll
        for (int i = 0; i < 2; ++i) {
            *(uint4*)&As[r0 + i * 64][c8] = pa[i];
            *(uint4*)&Bs[r0 + i * 64][c8] = pb[i];
        }
        __syncthreads();
        if (c < 15) load(c + 1);
        F8 af[4], bfr[4];
        #pragma unroll
        for (int x = 0; x < 4; ++x) {
            af[x].u.lo  = *(const unsigned long long*)&As[arow + x * 16][kg];
            af[x].u.hi  = *(const unsigned long long*)&As[arow + x * 16][16 + kg];
            bfr[x].u.lo = *(const unsigned long long*)&Bs[brow + x * 16][kg];
            bfr[x].u.hi = *(const unsigned long long*)&Bs[brow + x * 16][16 + kg];
        }
        #pragma unroll
        for (int mi = 0; mi < 4; ++mi)
            #pragma unroll
            for (int ni = 0; ni < 4; ++ni)
                acc[mi][ni] = __builtin_amdgcn_mfma_f32_16x16x32_bf16(
                    af[mi].v, bfr[ni].v, acc[mi][ni], 0, 0, 0);
    }

    const int crow = (lane >> 4) * 4, ccol = lane & 15;
    #pragma unroll
    for (int mi = 0; mi < 4; ++mi) {
        #pragma unroll
        for (int ni = 0; ni < 4; ++ni) {
            int n = n0 + wc * 64 + ni * 16 + ccol;
            if (n >= Vv) continue;
            float bo = b_out[n];
            #pragma unroll
            for (int r = 0; r < 4; ++r) {
                int m = m0 + wr * 64 + mi * 16 + crow + r;
                int t = m >> 6, b = m & 63;
                preds[(size_t)(b * Tt + t) * Vv + n] = acc[mi][ni][r] + bo;
            }
        }
    }
}

extern "C" void kernel_launch(void* const* d_in, const int* in_sizes, int n_in,
                              void* d_out, int out_size, void* d_ws, size_t ws_size,
                              hipStream_t stream) {
    const float* img_feat  = (const float*)d_in[0];
    const int*   captions  = (const int*)d_in[1];
    const float* embedding = (const float*)d_in[2];
    const float* W_enc_att = (const float*)d_in[3];
    const float* W_full    = (const float*)d_in[7];
    const float* W_beta    = (const float*)d_in[9];
    const float* b_beta    = (const float*)d_in[10];
    const float* W_ih      = (const float*)d_in[11];
    const float* b_ih      = (const float*)d_in[12];
    const float* W_hh      = (const float*)d_in[13];
    const float* b_hh      = (const float*)d_in[14];
    const float* W_init_h  = (const float*)d_in[15];
    const float* b_init_h  = (const float*)d_in[16];
    const float* W_init_c  = (const float*)d_in[17];
    const float* b_init_c  = (const float*)d_in[18];
    const float* W_out     = (const float*)d_in[19];
    const float* b_out     = (const float*)d_in[20];

    float* preds_out  = (float*)d_out;
    float* alphas_out = (float*)d_out + (size_t)Bsz * Tt * Vv;

    float* ws = (float*)d_ws;
    float* v_enc    = ws;                         // 2048
    float* sc       = v_enc + ENC;                // 12544
    float* alpha    = sc + Bsz * Pp;              // 12544
    float* context  = alpha + Bsz * Pp;           // 131072
    float* avg      = context + Bsz * ENC;        // 131072
    float* hc       = avg + Bsz * ENC;            // 65536 (h | c)
    float* gc       = hc + Bsz * 1024;            // 131072
    float* Pbuf     = gc + Bsz * ENC;             // 5 * 131072 partials
    float* emb_part = Pbuf + 5 * Bsz * H4;        // 1280*2048 gates prefill
    unsigned short* H_bf16 = (unsigned short*)(emb_part + (size_t)Tt * Bsz * H4); // 1280*512 bf16
    unsigned short* Wout_bf16 = (unsigned short*)emb_part; // alias: used only after loop

    // attention (timestep-invariant)
    k_venc<<<32, 256, 0, stream>>>(W_full, W_enc_att, v_enc);
    k_scores<<<dim3(49, 64), 256, 0, stream>>>(img_feat, v_enc, sc);
    k_softmax<<<64, 256, 0, stream>>>(sc, alpha, alphas_out);
    k_ctx<<<dim3(4, 64), 256, 0, stream>>>(img_feat, alpha, context, avg);

    // hc init
    gemm_step<0><<<64, 256, 0, stream>>>(
        avg, W_init_h, W_init_c, hc, nullptr, b_init_h, b_init_c, nullptr);

    // embedding part of gates for all steps (gather fused)
    gemm_emb<<<dim3(H4 / 64, (Tt * Bsz) / 128), 256, 0, stream>>>(
        captions, embedding, W_ih, emb_part, b_ih, b_hh);

    for (int t = 0; t < Tt; ++t) {
        // G1: h @ [W_beta | W_hh]^T  -> gc (gated) and P[0]
        gemm_step<1><<<256, 256, 0, stream>>>(
            hc, W_beta, W_hh, gc, Pbuf, b_beta, nullptr, context);
        // G2: gc @ W_ih[:, E:]^T, K split 4 ways -> P[1..4]
        gemm_step<2><<<dim3(128, 4), 256, 0, stream>>>(
            gc, W_ih, nullptr, nullptr, Pbuf, nullptr, nullptr, nullptr);
        // LSTM pointwise (sums emb part + 5 partials), writes h/c and bf16 H
        k_lstm<<<128, 256, 0, stream>>>(
            emb_part + (size_t)t * Bsz * H4, Pbuf, hc,
            H_bf16 + (size_t)t * Bsz * Hh);
    }

    // W_out -> bf16 (into emb_part alias; gates no longer needed)
    k_cvt<<<(Vv * Hh / 4 + 255) / 256, 256, 0, stream>>>(W_out, Wout_bf16);

    // preds via bf16 MFMA
    gemm_preds<<<dim3((Vv + 127) / 128, (Tt * Bsz) / 128), 256, 0, stream>>>(
        H_bf16, Wout_bf16, b_out, preds_out);
}